// Round 2
// baseline (726.707 us; speedup 1.0000x reference)
//
#include <hip/hip_runtime.h>
#include <hip/hip_bf16.h>
#include <stdint.h>

// ---------------------------------------------------------------------------
// Self-attention forward, B=4 S=4096 D=1024, fp32 in -> FP32 OUT (ref is f32).
// Pipeline: x->bf16; W^T->bf16; Q,K (NT gemm + bias); Vt = Wv^T x^T (+bias row);
// per batch: scores=Q K^T /32 -> softmax rows -> out = P Vt^T (f32 store).
// GEMM: m97 structure, 128x128 tile, BK=32, 4 waves, global_load_lds(16B).
// ---------------------------------------------------------------------------

#define BM 128
#define BN 128
#define BK 32

typedef __attribute__((ext_vector_type(8))) short bf16x8;
typedef __attribute__((ext_vector_type(4))) float f32x4;

static __device__ __forceinline__ unsigned short f2b(float f) {
  union { float f; unsigned u; } x; x.f = f;
  unsigned u = x.u;
  u += 0x7fffu + ((u >> 16) & 1u);      // RNE
  return (unsigned short)(u >> 16);
}
static __device__ __forceinline__ float b2f(unsigned short s) {
  union { unsigned u; float f; } x; x.u = ((unsigned)s) << 16;
  return x.f;
}

// async global->LDS, 16B per lane. LDS dest: wave-uniform base + lane*16.
static __device__ __forceinline__ void gl_lds16(const void* g, void* l) {
  __builtin_amdgcn_global_load_lds(
      (const __attribute__((address_space(1))) void*)(uintptr_t)(g),
      (__attribute__((address_space(3))) void*)(uint32_t)(uintptr_t)(l),
      16, 0, 0);
}

// ---------------------------------------------------------------------------
// f32 -> bf16 vectorized convert (8 elems/thread)
// ---------------------------------------------------------------------------
__global__ void convert_x(const float* __restrict__ in,
                          unsigned short* __restrict__ out, int n8) {
  int i = blockIdx.x * blockDim.x + threadIdx.x;
  if (i >= n8) return;
  const float4* p = (const float4*)in + (size_t)i * 2;
  float4 a = p[0], b = p[1];
  bf16x8 o;
  o[0] = (short)f2b(a.x); o[1] = (short)f2b(a.y);
  o[2] = (short)f2b(a.z); o[3] = (short)f2b(a.w);
  o[4] = (short)f2b(b.x); o[5] = (short)f2b(b.y);
  o[6] = (short)f2b(b.z); o[7] = (short)f2b(b.w);
  ((bf16x8*)out)[i] = o;
}

// ---------------------------------------------------------------------------
// W [1024][1024] f32 -> W^T [1024][1024] bf16, 32x32 LDS tiles
// ---------------------------------------------------------------------------
__global__ void transpose_w(const float* __restrict__ in,
                            unsigned short* __restrict__ out) {
  __shared__ float tile[32][33];
  const int tx = threadIdx.x;            // 0..31
  const int x = blockIdx.x * 32 + tx;
  const int y0 = blockIdx.y * 32;
  for (int j = threadIdx.y; j < 32; j += 8)
    tile[j][tx] = in[(size_t)(y0 + j) * 1024 + x];
  __syncthreads();
  const int ox = blockIdx.y * 32 + tx;
  const int oy0 = blockIdx.x * 32;
  for (int j = threadIdx.y; j < 32; j += 8)
    out[(size_t)(oy0 + j) * 1024 + ox] = f2b(tile[tx][j]);
}

// ---------------------------------------------------------------------------
// NT GEMM: C[m][n] = alpha * sum_k A[m][k]*B[n][k]  (+ bias)
// A: [M][lda] bf16, B: [N][ldb] bf16.
// C: bf16 if OUTF==0, f32 if OUTF==1 (stride ldc elements either way).
// bias_mode: 0 none, 1 per-col (bias[n]), 2 per-row (bias[m])
// Requires M%128==0, N%128==0, K%32==0.
// ---------------------------------------------------------------------------
template <int OUTF>
__global__ __launch_bounds__(256, 2)
void gemm_nt(const unsigned short* __restrict__ A, long lda,
             const unsigned short* __restrict__ B, long ldb,
             void* __restrict__ Cv, long ldc,
             const float* __restrict__ bias, int bias_mode,
             int K, float alpha) {
  __shared__ __align__(16) unsigned short As[BM * BK];
  __shared__ __align__(16) unsigned short Bs[BN * BK];

  const int t = threadIdx.x;
  const long bm = (long)blockIdx.y * BM;
  const long bn = (long)blockIdx.x * BN;
  const int w = t >> 6, lane = t & 63;
  const int wm = (w >> 1) * 64;          // wave tile row (2x2 waves of 64x64)
  const int wn = (w & 1) * 64;
  const int fr = lane & 15;              // fragment row/col
  const int fq = lane >> 4;              // quad 0..3

  f32x4 acc[4][4] = {};

  // staging: per call, 256 threads x 16B = 64 rows x 32cols(bf16).
  const int strow = t >> 2;              // 0..63
  const int stcol = (t & 3) * 8;
  const unsigned short* Ag = A + (bm + strow) * lda + stcol;
  const unsigned short* Bg = B + (bn + strow) * ldb + stcol;
  unsigned short* AsW = As + (size_t)w * 512;  // wave-uniform LDS base (call 0)
  unsigned short* BsW = Bs + (size_t)w * 512;

  for (int k = 0; k < K; k += BK) {
    gl_lds16(Ag + k, AsW);
    gl_lds16(Ag + k + 64 * lda, AsW + 2048);
    gl_lds16(Bg + k, BsW);
    gl_lds16(Bg + k + 64 * ldb, BsW + 2048);
    __syncthreads();                     // compiler drains vmcnt before barrier

    bf16x8 av[4], bvf[4];
#pragma unroll
    for (int i = 0; i < 4; i++)
      av[i] = *(const bf16x8*)(As + (wm + i * 16 + fr) * BK + fq * 8);
#pragma unroll
    for (int j = 0; j < 4; j++)
      bvf[j] = *(const bf16x8*)(Bs + (wn + j * 16 + fr) * BK + fq * 8);

#pragma unroll
    for (int i = 0; i < 4; i++)
#pragma unroll
      for (int j = 0; j < 4; j++)
        acc[i][j] = __builtin_amdgcn_mfma_f32_16x16x32_bf16(
            av[i], bvf[j], acc[i][j], 0, 0, 0);
    __syncthreads();
  }

  // epilogue: C/D layout col=lane&15, row=(lane>>4)*4+reg  [m89/m91]
  const long crow = bm + wm + fq * 4;
  const long ccol = bn + wn + fr;
#pragma unroll
  for (int i = 0; i < 4; i++) {
#pragma unroll
    for (int j = 0; j < 4; j++) {
      const long col = ccol + j * 16;
      float badd_c = (bias_mode == 1) ? bias[col] : 0.0f;
#pragma unroll
      for (int r = 0; r < 4; r++) {
        const long row = crow + i * 16 + r;
        float v = acc[i][j][r] * alpha + badd_c;
        if (bias_mode == 2) v += bias[row];
        if (OUTF)
          ((float*)Cv)[row * ldc + col] = v;
        else
          ((unsigned short*)Cv)[row * ldc + col] = f2b(v);
      }
    }
  }
}

// ---------------------------------------------------------------------------
// In-place row softmax over bf16 rows of length 4096. One block (256thr)/row.
// ---------------------------------------------------------------------------
__global__ __launch_bounds__(256)
void softmax_rows(unsigned short* __restrict__ S) {
  const int t = threadIdx.x;
  unsigned short* row = S + (size_t)blockIdx.x * 4096;
  const bf16x8* p = (const bf16x8*)row;
  bf16x8 u0 = p[t * 2], u1 = p[t * 2 + 1];

  float v[16];
  float m = -1e30f;
#pragma unroll
  for (int j = 0; j < 8; j++) { v[j] = b2f((unsigned short)u0[j]); }
#pragma unroll
  for (int j = 0; j < 8; j++) { v[8 + j] = b2f((unsigned short)u1[j]); }
#pragma unroll
  for (int j = 0; j < 16; j++) m = fmaxf(m, v[j]);

#pragma unroll
  for (int off = 32; off > 0; off >>= 1) m = fmaxf(m, __shfl_xor(m, off));
  __shared__ float redm[4];
  if ((t & 63) == 0) redm[t >> 6] = m;
  __syncthreads();
  m = fmaxf(fmaxf(redm[0], redm[1]), fmaxf(redm[2], redm[3]));

  float s = 0.0f;
#pragma unroll
  for (int j = 0; j < 16; j++) { v[j] = __expf(v[j] - m); s += v[j]; }
#pragma unroll
  for (int off = 32; off > 0; off >>= 1) s += __shfl_xor(s, off);
  __shared__ float reds[4];
  if ((t & 63) == 0) reds[t >> 6] = s;
  __syncthreads();
  s = reds[0] + reds[1] + reds[2] + reds[3];
  const float inv = 1.0f / s;

  bf16x8 o0, o1;
#pragma unroll
  for (int j = 0; j < 8; j++) o0[j] = (short)f2b(v[j] * inv);
#pragma unroll
  for (int j = 0; j < 8; j++) o1[j] = (short)f2b(v[8 + j] * inv);
  bf16x8* q = (bf16x8*)row;
  q[t * 2] = o0;
  q[t * 2 + 1] = o1;
}

// ---------------------------------------------------------------------------
extern "C" void kernel_launch(void* const* d_in, const int* in_sizes, int n_in,
                              void* d_out, int out_size, void* d_ws,
                              size_t ws_size, hipStream_t stream) {
  const float* x  = (const float*)d_in[0];
  const float* Wq = (const float*)d_in[1];
  const float* bq = (const float*)d_in[2];
  const float* Wk = (const float*)d_in[3];
  const float* bk = (const float*)d_in[4];
  const float* Wv = (const float*)d_in[5];
  const float* bv = (const float*)d_in[6];
  float* out = (float*)d_out;                     // reference output is f32

  const int Bb = 4, S = 4096, D = 1024;
  const long BS = (long)Bb * S;                   // 16384

  char* ws = (char*)d_ws;
  unsigned short* xb  = (unsigned short*)ws; ws += BS * D * 2;        // 33.5MB
  unsigned short* Wqt = (unsigned short*)ws; ws += (long)D * D * 2;
  unsigned short* Wkt = (unsigned short*)ws; ws += (long)D * D * 2;
  unsigned short* Wvt = (unsigned short*)ws; ws += (long)D * D * 2;
  unsigned short* Qb  = (unsigned short*)ws; ws += BS * D * 2;
  unsigned short* Kb  = (unsigned short*)ws; ws += BS * D * 2;
  unsigned short* Vt  = (unsigned short*)ws; ws += (long)D * BS * 2;  // [D][B*S]
  unsigned short* Sb  = xb;  // scores buffer aliases xb (dead after projections)

  // 1. x -> bf16
  const int n8 = (int)(BS * D / 8);
  convert_x<<<n8 / 256, 256, 0, stream>>>(x, xb, n8);

  // 2. W -> W^T bf16
  dim3 tb(32, 8), tg(32, 32);
  transpose_w<<<tg, tb, 0, stream>>>(Wq, Wqt);
  transpose_w<<<tg, tb, 0, stream>>>(Wk, Wkt);
  transpose_w<<<tg, tb, 0, stream>>>(Wv, Wvt);

  // 3. projections (bf16 out)
  gemm_nt<0><<<dim3(D / BN, BS / BM), 256, 0, stream>>>(
      xb, D, Wqt, D, Qb, D, bq, 1, D, 1.0f);
  gemm_nt<0><<<dim3(D / BN, BS / BM), 256, 0, stream>>>(
      xb, D, Wkt, D, Kb, D, bk, 1, D, 1.0f);
  // Vt[d][b*S+s] = V[b,s,d] : A=Wv^T [D][D], B=xb [BS][D], bias per-row
  gemm_nt<0><<<dim3(BS / BN, D / BM), 256, 0, stream>>>(
      Wvt, D, xb, D, Vt, BS, bv, 2, D, 1.0f);

  // 4. attention per batch
  const float scale = 0.03125f;  // 1/sqrt(1024)
  for (int b = 0; b < Bb; b++) {
    const unsigned short* Qp = Qb + (long)b * S * D;
    const unsigned short* Kp = Kb + (long)b * S * D;
    gemm_nt<0><<<dim3(S / BN, S / BM), 256, 0, stream>>>(
        Qp, D, Kp, D, Sb, S, nullptr, 0, D, scale);
    softmax_rows<<<S, 256, 0, stream>>>(Sb);
    const unsigned short* Vp = Vt + (long)b * S;  // column offset into [D][BS]
    float* Op = out + (long)b * S * D;
    gemm_nt<1><<<dim3(D / BN, S / BM), 256, 0, stream>>>(
        Sb, S, Vp, BS, Op, D, nullptr, 0, S, 1.0f);
  }
}

// Round 3
// 483.277 us; speedup vs baseline: 1.5037x; 1.5037x over previous
//
#include <hip/hip_runtime.h>
#include <hip/hip_bf16.h>
#include <stdint.h>

// ---------------------------------------------------------------------------
// Self-attention forward, B=4 S=4096 D=1024, fp32 in -> f32 out.
// GEMM: 256x256 tile, BK=64, 8 waves, 8-phase-style schedule with counted
// vmcnt (T3+T4), LDS XOR swizzle (T2), setprio around MFMA (T5).
// ---------------------------------------------------------------------------

typedef __attribute__((ext_vector_type(8))) short bf16x8;
typedef __attribute__((ext_vector_type(4))) float f32x4;

static __device__ __forceinline__ unsigned short f2b(float f) {
  union { float f; unsigned u; } x; x.f = f;
  unsigned u = x.u;
  u += 0x7fffu + ((u >> 16) & 1u);      // RNE
  return (unsigned short)(u >> 16);
}
static __device__ __forceinline__ float b2f(unsigned short s) {
  union { unsigned u; float f; } x; x.u = ((unsigned)s) << 16;
  return x.f;
}

// async global->LDS, 16B per lane. LDS dest: wave-uniform base + lane*16.
static __device__ __forceinline__ void gl_lds16(const void* g, void* l) {
  __builtin_amdgcn_global_load_lds(
      (const __attribute__((address_space(1))) void*)(uintptr_t)(g),
      (__attribute__((address_space(3))) void*)(uint32_t)(uintptr_t)(l),
      16, 0, 0);
}

// ---------------------------------------------------------------------------
__global__ void convert_x(const float* __restrict__ in,
                          unsigned short* __restrict__ out, int n8) {
  int i = blockIdx.x * blockDim.x + threadIdx.x;
  if (i >= n8) return;
  const float4* p = (const float4*)in + (size_t)i * 2;
  float4 a = p[0], b = p[1];
  bf16x8 o;
  o[0] = (short)f2b(a.x); o[1] = (short)f2b(a.y);
  o[2] = (short)f2b(a.z); o[3] = (short)f2b(a.w);
  o[4] = (short)f2b(b.x); o[5] = (short)f2b(b.y);
  o[6] = (short)f2b(b.z); o[7] = (short)f2b(b.w);
  ((bf16x8*)out)[i] = o;
}

__global__ void transpose_w(const float* __restrict__ in,
                            unsigned short* __restrict__ out) {
  __shared__ float tile[32][33];
  const int tx = threadIdx.x;
  const int x = blockIdx.x * 32 + tx;
  const int y0 = blockIdx.y * 32;
  for (int j = threadIdx.y; j < 32; j += 8)
    tile[j][tx] = in[(size_t)(y0 + j) * 1024 + x];
  __syncthreads();
  const int ox = blockIdx.y * 32 + tx;
  const int oy0 = blockIdx.x * 32;
  for (int j = threadIdx.y; j < 32; j += 8)
    out[(size_t)(oy0 + j) * 1024 + ox] = f2b(tile[tx][j]);
}

// ---------------------------------------------------------------------------
// 256x256 NT GEMM, BK=64, 512 threads (8 waves, 2x4), dbuf LDS, counted vmcnt.
// C[m][n] = alpha * sum_k A[m][k]*B[n][k] (+bias). z-batched via strides.
// Requires M%256==0, N%256==0, K%64==0, K>=192.
// ---------------------------------------------------------------------------
template <int OUTF>
__global__ __launch_bounds__(512, 2)
void gemm256(const unsigned short* __restrict__ A, long lda, long sAz,
             const unsigned short* __restrict__ B, long ldb, long sBz,
             void* __restrict__ Cv, long ldc, long sCz,
             const float* __restrict__ bias, int bias_mode,
             int K, float alpha) {
  __shared__ __align__(16) unsigned short As[2][256 * 64];
  __shared__ __align__(16) unsigned short Bs[2][256 * 64];

  const int t = threadIdx.x;
  const int wid = t >> 6, lane = t & 63;
  const int wm = wid >> 2, wn = wid & 3;      // 2x4 wave grid
  const int fr = lane & 15, fq = lane >> 4;
  const long bm = (long)blockIdx.y * 256;
  const long bn = (long)blockIdx.x * 256;
  const unsigned short* Ab = A + (size_t)blockIdx.z * sAz;
  const unsigned short* Bb = B + (size_t)blockIdx.z * sBz;

  // staging: one gl_lds call = 512 lanes x 16B = 64 rows x 64 cols bf16.
  // pre-swizzled global source (rule #21): col granule ^= row&7.
  const int sr = t >> 3;                       // 0..63 row in chunk
  const int scol = 8 * ((t & 7) ^ (sr & 7));   // swizzled col (elements)
  const unsigned short* Ag = Ab + (bm + sr) * lda + scol;
  const unsigned short* Bg = Bb + (bn + sr) * ldb + scol;
  const int ldsw = wid * 512;                  // wave chunk base (shorts)

  const int NT = K >> 6;
  f32x4 acc[8][4] = {};

#define STAGE(XS, Xg, ld, kt, h, bidx)                                        \
  do {                                                                        \
    gl_lds16(Xg + (size_t)((h) * 128) * (ld) + (size_t)(kt) * 64,             \
             &XS[bidx][(h) * 128 * 64 + ldsw]);                               \
    gl_lds16(Xg + (size_t)((h) * 128 + 64) * (ld) + (size_t)(kt) * 64,        \
             &XS[bidx][((h) * 128 + 64) * 64 + ldsw]);                        \
  } while (0)

  // swizzled ds_read: row-major [256][64] bf16, byte ^= (row&7)<<4
  auto rdA = [&](int bidx, int i, int kh) {
    int row = wm * 128 + i * 16 + fr;
    int inb = (kh * 64 + fq * 16) ^ ((fr & 7) << 4);
    return *(const bf16x8*)((const char*)&As[bidx][0] + row * 128 + inb);
  };
  auto rdB = [&](int bidx, int j, int kh) {
    int row = wn * 64 + j * 16 + fr;
    int inb = (kh * 64 + fq * 16) ^ ((fr & 7) << 4);
    return *(const bf16x8*)((const char*)&Bs[bidx][0] + row * 128 + inb);
  };

  // prologue: tile0 (A,B) + tile1 B; leave tile1's B (4 loads) in flight.
  STAGE(As, Ag, lda, 0, 0, 0); STAGE(As, Ag, lda, 0, 1, 0);
  STAGE(Bs, Bg, ldb, 0, 0, 0); STAGE(Bs, Bg, ldb, 0, 1, 0);
  STAGE(Bs, Bg, ldb, 1, 0, 1); STAGE(Bs, Bg, ldb, 1, 1, 1);
  asm volatile("s_waitcnt vmcnt(4)" ::: "memory");
  asm volatile("s_barrier" ::: "memory");

  bf16x8 bfr[4][2];
  for (int tt = 0; tt < NT; ++tt) {
    const int bidx = tt & 1;
#pragma unroll
    for (int p = 0; p < 4; ++p) {
      bf16x8 ar[2][2];
      if (p == 0) {
#pragma unroll
        for (int j = 0; j < 4; ++j) {
          bfr[j][0] = rdB(bidx, j, 0);
          bfr[j][1] = rdB(bidx, j, 1);
        }
      }
#pragma unroll
      for (int ii = 0; ii < 2; ++ii) {
        ar[ii][0] = rdA(bidx, p * 2 + ii, 0);
        ar[ii][1] = rdA(bidx, p * 2 + ii, 1);
      }
      // staging schedule: A(t+1) at p0/p1 (other buffer);
      // B(t+2) at p2/p3 (current buffer; B reads all completed at p0).
      if (p == 0 && tt + 1 < NT) STAGE(As, Ag, lda, tt + 1, 0, (tt + 1) & 1);
      if (p == 1 && tt + 1 < NT) STAGE(As, Ag, lda, tt + 1, 1, (tt + 1) & 1);
      if (p == 2 && tt + 2 < NT) STAGE(Bs, Bg, ldb, tt + 2, 0, tt & 1);
      if (p == 3 && tt + 2 < NT) STAGE(Bs, Bg, ldb, tt + 2, 1, tt & 1);
      asm volatile("s_barrier" ::: "memory");
      __builtin_amdgcn_s_setprio(1);
#pragma unroll
      for (int ii = 0; ii < 2; ++ii)
#pragma unroll
        for (int j = 0; j < 4; ++j) {
          acc[p * 2 + ii][j] = __builtin_amdgcn_mfma_f32_16x16x32_bf16(
              ar[ii][0], bfr[j][0], acc[p * 2 + ii][j], 0, 0, 0);
          acc[p * 2 + ii][j] = __builtin_amdgcn_mfma_f32_16x16x32_bf16(
              ar[ii][1], bfr[j][1], acc[p * 2 + ii][j], 0, 0, 0);
        }
      __builtin_amdgcn_s_setprio(0);
      if (p == 3) {
        // boundary wait: keep last 4 loads (B(t+2)) in flight, never 0
        // mid-loop; drain fully before the final tile.
        if (tt + 2 < NT)
          asm volatile("s_waitcnt vmcnt(4)" ::: "memory");
        else if (tt + 1 < NT)
          asm volatile("s_waitcnt vmcnt(0)" ::: "memory");
      }
      asm volatile("s_barrier" ::: "memory");
    }
  }
#undef STAGE

  // epilogue: C/D layout col=lane&15, row=(lane>>4)*4+reg  [m89/m91]
  char* Cb = (char*)Cv + (size_t)blockIdx.z * sCz * (OUTF ? 4 : 2);
  const long crow0 = bm + wm * 128 + fq * 4;
  const long ccol0 = bn + wn * 64 + fr;
#pragma unroll
  for (int i = 0; i < 8; ++i) {
#pragma unroll
    for (int j = 0; j < 4; ++j) {
      const long col = ccol0 + j * 16;
      float badd_c = (bias_mode == 1) ? bias[col] : 0.0f;
#pragma unroll
      for (int r = 0; r < 4; ++r) {
        const long row = crow0 + i * 16 + r;
        float v = acc[i][j][r] * alpha + badd_c;
        if (bias_mode == 2) v += bias[row];
        if (OUTF)
          ((float*)Cb)[row * ldc + col] = v;
        else
          ((unsigned short*)Cb)[row * ldc + col] = f2b(v);
      }
    }
  }
}

// ---------------------------------------------------------------------------
// In-place row softmax over bf16 rows of length 4096. One block (256thr)/row.
// ---------------------------------------------------------------------------
__global__ __launch_bounds__(256)
void softmax_rows(unsigned short* __restrict__ S) {
  const int t = threadIdx.x;
  unsigned short* row = S + (size_t)blockIdx.x * 4096;
  const bf16x8* p = (const bf16x8*)row;
  bf16x8 u0 = p[t * 2], u1 = p[t * 2 + 1];

  float v[16];
  float m = -1e30f;
#pragma unroll
  for (int j = 0; j < 8; j++) { v[j] = b2f((unsigned short)u0[j]); }
#pragma unroll
  for (int j = 0; j < 8; j++) { v[8 + j] = b2f((unsigned short)u1[j]); }
#pragma unroll
  for (int j = 0; j < 16; j++) m = fmaxf(m, v[j]);

#pragma unroll
  for (int off = 32; off > 0; off >>= 1) m = fmaxf(m, __shfl_xor(m, off));
  __shared__ float redm[4];
  if ((t & 63) == 0) redm[t >> 6] = m;
  __syncthreads();
  m = fmaxf(fmaxf(redm[0], redm[1]), fmaxf(redm[2], redm[3]));

  float s = 0.0f;
#pragma unroll
  for (int j = 0; j < 16; j++) { v[j] = __expf(v[j] - m); s += v[j]; }
#pragma unroll
  for (int off = 32; off > 0; off >>= 1) s += __shfl_xor(s, off);
  __shared__ float reds[4];
  if ((t & 63) == 0) reds[t >> 6] = s;
  __syncthreads();
  s = reds[0] + reds[1] + reds[2] + reds[3];
  const float inv = 1.0f / s;

  bf16x8 o0, o1;
#pragma unroll
  for (int j = 0; j < 8; j++) o0[j] = (short)f2b(v[j] * inv);
#pragma unroll
  for (int j = 0; j < 8; j++) o1[j] = (short)f2b(v[8 + j] * inv);
  bf16x8* q = (bf16x8*)row;
  q[t * 2] = o0;
  q[t * 2 + 1] = o1;
}

// ---------------------------------------------------------------------------
extern "C" void kernel_launch(void* const* d_in, const int* in_sizes, int n_in,
                              void* d_out, int out_size, void* d_ws,
                              size_t ws_size, hipStream_t stream) {
  const float* x  = (const float*)d_in[0];
  const float* Wq = (const float*)d_in[1];
  const float* bq = (const float*)d_in[2];
  const float* Wk = (const float*)d_in[3];
  const float* bk = (const float*)d_in[4];
  const float* Wv = (const float*)d_in[5];
  const float* bv = (const float*)d_in[6];
  float* out = (float*)d_out;

  const int Bb = 4, S = 4096, D = 1024;
  const long BS = (long)Bb * S;                 // 16384
  const size_t MiB = 1u << 20;

  char* base = (char*)d_ws;
  unsigned short* Wqt = (unsigned short*)(base);              // 2 MiB
  unsigned short* Wkt = (unsigned short*)(base + 2 * MiB);    // 2
  unsigned short* Wvt = (unsigned short*)(base + 4 * MiB);    // 2
  unsigned short* Qb  = (unsigned short*)(base + 6 * MiB);    // 32
  unsigned short* Kb  = (unsigned short*)(base + 38 * MiB);   // 32
  unsigned short* Vt  = (unsigned short*)(base + 70 * MiB);   // 32  [D][BS]
  unsigned short* xb  = (unsigned short*)(base + 102 * MiB);  // 32 (dies early)
  unsigned short* Sb  = xb;  // scores region overlaps dead xb
  const bool batched = ws_size >= (size_t)(102 + 128) * MiB;  // 4-batch scores

  // 1. x -> bf16
  const int n8 = (int)(BS * D / 8);
  convert_x<<<n8 / 256, 256, 0, stream>>>(x, xb, n8);

  // 2. W -> W^T bf16
  dim3 tb(32, 8), tg(32, 32);
  transpose_w<<<tg, tb, 0, stream>>>(Wq, Wqt);
  transpose_w<<<tg, tb, 0, stream>>>(Wk, Wkt);
  transpose_w<<<tg, tb, 0, stream>>>(Wv, Wvt);

  // 3. projections
  gemm256<0><<<dim3(D / 256, BS / 256, 1), 512, 0, stream>>>(
      xb, D, 0, Wqt, D, 0, Qb, D, 0, bq, 1, D, 1.0f);
  gemm256<0><<<dim3(D / 256, BS / 256, 1), 512, 0, stream>>>(
      xb, D, 0, Wkt, D, 0, Kb, D, 0, bk, 1, D, 1.0f);
  gemm256<0><<<dim3(BS / 256, D / 256, 1), 512, 0, stream>>>(
      Wvt, D, 0, xb, D, 0, Vt, BS, 0, bv, 2, D, 1.0f);

  // 4. attention
  const float scale = 0.03125f;  // 1/sqrt(1024)
  if (batched) {
    gemm256<0><<<dim3(S / 256, S / 256, Bb), 512, 0, stream>>>(
        Qb, D, (long)S * D, Kb, D, (long)S * D, Sb, S, (long)S * S,
        nullptr, 0, D, scale);
    softmax_rows<<<Bb * S, 256, 0, stream>>>(Sb);
    gemm256<1><<<dim3(D / 256, S / 256, Bb), 512, 0, stream>>>(
        Sb, S, (long)S * S, Vt, BS, (long)S, out, D, (long)S * D,
        nullptr, 0, S, 1.0f);
  } else {
    for (int b = 0; b < Bb; b++) {
      const unsigned short* Qp = Qb + (long)b * S * D;
      const unsigned short* Kp = Kb + (long)b * S * D;
      gemm256<0><<<dim3(S / 256, S / 256, 1), 512, 0, stream>>>(
          Qp, D, 0, Kp, D, 0, Sb, S, 0, nullptr, 0, D, scale);
      softmax_rows<<<S, 256, 0, stream>>>(Sb);
      gemm256<1><<<dim3(D / 256, S / 256, 1), 512, 0, stream>>>(
          Sb, S, 0, Vt + (long)b * S, BS, 0, out + (long)b * S * D, D, 0,
          nullptr, 0, S, 1.0f);
    }
  }
}

// Round 4
// 468.817 us; speedup vs baseline: 1.5501x; 1.0308x over previous
//
#include <hip/hip_runtime.h>
#include <hip/hip_bf16.h>
#include <stdint.h>

// ---------------------------------------------------------------------------
// Self-attention forward, B=4 S=4096 D=1024, fp32 in -> f32 out.
// GEMM: 256x256 tile, BK=64, 8 waves, dbuf LDS, ONE barrier + ONE vmcnt(0)
// per K-tile, A-frag reads software-pipelined under MFMA, LDS XOR swizzle,
// setprio around MFMA region.
// ---------------------------------------------------------------------------

typedef __attribute__((ext_vector_type(8))) short bf16x8;
typedef __attribute__((ext_vector_type(4))) float f32x4;

static __device__ __forceinline__ unsigned short f2b(float f) {
  union { float f; unsigned u; } x; x.f = f;
  unsigned u = x.u;
  u += 0x7fffu + ((u >> 16) & 1u);      // RNE
  return (unsigned short)(u >> 16);
}
static __device__ __forceinline__ float b2f(unsigned short s) {
  union { unsigned u; float f; } x; x.u = ((unsigned)s) << 16;
  return x.f;
}

// async global->LDS, 16B per lane. LDS dest: wave-uniform base + lane*16.
static __device__ __forceinline__ void gl_lds16(const void* g, void* l) {
  __builtin_amdgcn_global_load_lds(
      (const __attribute__((address_space(1))) void*)(uintptr_t)(g),
      (__attribute__((address_space(3))) void*)(uint32_t)(uintptr_t)(l),
      16, 0, 0);
}

// ---------------------------------------------------------------------------
__global__ void convert_x(const float* __restrict__ in,
                          unsigned short* __restrict__ out, int n8) {
  int i = blockIdx.x * blockDim.x + threadIdx.x;
  if (i >= n8) return;
  const float4* p = (const float4*)in + (size_t)i * 2;
  float4 a = p[0], b = p[1];
  bf16x8 o;
  o[0] = (short)f2b(a.x); o[1] = (short)f2b(a.y);
  o[2] = (short)f2b(a.z); o[3] = (short)f2b(a.w);
  o[4] = (short)f2b(b.x); o[5] = (short)f2b(b.y);
  o[6] = (short)f2b(b.z); o[7] = (short)f2b(b.w);
  ((bf16x8*)out)[i] = o;
}

__global__ void transpose_w(const float* __restrict__ in,
                            unsigned short* __restrict__ out) {
  __shared__ float tile[32][33];
  const int tx = threadIdx.x;
  const int x = blockIdx.x * 32 + tx;
  const int y0 = blockIdx.y * 32;
  for (int j = threadIdx.y; j < 32; j += 8)
    tile[j][tx] = in[(size_t)(y0 + j) * 1024 + x];
  __syncthreads();
  const int ox = blockIdx.y * 32 + tx;
  const int oy0 = blockIdx.x * 32;
  for (int j = threadIdx.y; j < 32; j += 8)
    out[(size_t)(oy0 + j) * 1024 + ox] = f2b(tile[tx][j]);
}

// ---------------------------------------------------------------------------
// 256x256 NT GEMM, BK=64, 512 threads (8 waves, 2x4), dbuf LDS.
// C[m][n] = alpha * sum_k A[m][k]*B[n][k] (+bias). z-batched via strides.
// Requires M%256==0, N%256==0, K%64==0.
// ---------------------------------------------------------------------------
template <int OUTF>
__global__ __launch_bounds__(512, 2)
void gemm256(const unsigned short* __restrict__ A, long lda, long sAz,
             const unsigned short* __restrict__ B, long ldb, long sBz,
             void* __restrict__ Cv, long ldc, long sCz,
             const float* __restrict__ bias, int bias_mode,
             int K, float alpha) {
  __shared__ __align__(16) unsigned short As[2][256 * 64];
  __shared__ __align__(16) unsigned short Bs[2][256 * 64];

  const int t = threadIdx.x;
  const int wid = t >> 6, lane = t & 63;
  const int wm = wid >> 2, wn = wid & 3;      // 2x4 wave grid
  const int fr = lane & 15, fq = lane >> 4;
  const long bm = (long)blockIdx.y * 256;
  const long bn = (long)blockIdx.x * 256;
  const unsigned short* Ab = A + (size_t)blockIdx.z * sAz;
  const unsigned short* Bb = B + (size_t)blockIdx.z * sBz;

  // staging: one gl_lds call = 512 lanes x 16B = 64 rows x 64 cols bf16.
  // pre-swizzled global source (rule #21): col granule ^= row&7.
  const int sr = t >> 3;                       // 0..63 row in chunk
  const int scol = 8 * ((t & 7) ^ (sr & 7));   // swizzled col (elements)
  const unsigned short* Ag = Ab + (bm + sr) * lda + scol;
  const unsigned short* Bg = Bb + (bn + sr) * ldb + scol;
  const int ldsw = wid * 512;                  // wave chunk base (shorts)

  const int NT = K >> 6;
  f32x4 acc[8][4] = {};

#define STAGE(XS, Xg, ld, kt, h, bidx)                                        \
  do {                                                                        \
    gl_lds16(Xg + (size_t)((h) * 128) * (ld) + (size_t)(kt) * 64,             \
             &XS[bidx][(h) * 128 * 64 + ldsw]);                               \
    gl_lds16(Xg + (size_t)((h) * 128 + 64) * (ld) + (size_t)(kt) * 64,        \
             &XS[bidx][((h) * 128 + 64) * 64 + ldsw]);                        \
  } while (0)

  // swizzled ds_read: row-major [256][64] bf16, byte ^= (row&7)<<4
  auto rdA = [&](int bidx, int i, int kh) {
    int row = wm * 128 + i * 16 + fr;
    int inb = (kh * 64 + fq * 16) ^ ((fr & 7) << 4);
    return *(const bf16x8*)((const char*)&As[bidx][0] + row * 128 + inb);
  };
  auto rdB = [&](int bidx, int j, int kh) {
    int row = wn * 64 + j * 16 + fr;
    int inb = (kh * 64 + fq * 16) ^ ((fr & 7) << 4);
    return *(const bf16x8*)((const char*)&Bs[bidx][0] + row * 128 + inb);
  };

  // prologue: stage tile 0, drain, sync.
  STAGE(As, Ag, lda, 0, 0, 0); STAGE(As, Ag, lda, 0, 1, 0);
  STAGE(Bs, Bg, ldb, 0, 0, 0); STAGE(Bs, Bg, ldb, 0, 1, 0);
  asm volatile("s_waitcnt vmcnt(0)" ::: "memory");
  asm volatile("s_barrier" ::: "memory");

  for (int tt = 0; tt < NT; ++tt) {
    const int bidx = tt & 1;
    const int nb = (tt + 1) & 1;
    bf16x8 bfr[4][2], ar[2][2], arn[2][2];

    // all 8 B-frags + first A-pair
#pragma unroll
    for (int j = 0; j < 4; ++j) {
      bfr[j][0] = rdB(bidx, j, 0);
      bfr[j][1] = rdB(bidx, j, 1);
    }
#pragma unroll
    for (int ii = 0; ii < 2; ++ii) {
      ar[ii][0] = rdA(bidx, ii, 0);
      ar[ii][1] = rdA(bidx, ii, 1);
    }

    // stage tile t+1 as early as possible (writes land in the other buffer;
    // safe: that buffer's readers all finished before the last barrier).
    if (tt + 1 < NT) {
      STAGE(As, Ag, lda, tt + 1, 0, nb); STAGE(As, Ag, lda, tt + 1, 1, nb);
      STAGE(Bs, Bg, ldb, tt + 1, 0, nb); STAGE(Bs, Bg, ldb, tt + 1, 1, nb);
    }

    __builtin_amdgcn_s_setprio(1);
#pragma unroll
    for (int p = 0; p < 4; ++p) {
      // prefetch next A-pair into regs so its latency hides under this MFMA
      if (p < 3) {
#pragma unroll
        for (int ii = 0; ii < 2; ++ii) {
          arn[ii][0] = rdA(bidx, (p + 1) * 2 + ii, 0);
          arn[ii][1] = rdA(bidx, (p + 1) * 2 + ii, 1);
        }
      }
#pragma unroll
      for (int ii = 0; ii < 2; ++ii)
#pragma unroll
        for (int j = 0; j < 4; ++j) {
          acc[p * 2 + ii][j] = __builtin_amdgcn_mfma_f32_16x16x32_bf16(
              ar[ii][0], bfr[j][0], acc[p * 2 + ii][j], 0, 0, 0);
          acc[p * 2 + ii][j] = __builtin_amdgcn_mfma_f32_16x16x32_bf16(
              ar[ii][1], bfr[j][1], acc[p * 2 + ii][j], 0, 0, 0);
        }
      if (p < 3) {
#pragma unroll
        for (int ii = 0; ii < 2; ++ii) {
          ar[ii][0] = arn[ii][0];
          ar[ii][1] = arn[ii][1];
        }
      }
    }
    __builtin_amdgcn_s_setprio(0);

    // single drain + single barrier per K-tile (buffer transition).
    asm volatile("s_waitcnt vmcnt(0)" ::: "memory");
    asm volatile("s_barrier" ::: "memory");
  }
#undef STAGE

  // epilogue: C/D layout col=lane&15, row=(lane>>4)*4+reg  [m89/m91]
  char* Cb = (char*)Cv + (size_t)blockIdx.z * sCz * (OUTF ? 4 : 2);
  const long crow0 = bm + wm * 128 + fq * 4;
  const long ccol0 = bn + wn * 64 + fr;
#pragma unroll
  for (int i = 0; i < 8; ++i) {
#pragma unroll
    for (int j = 0; j < 4; ++j) {
      const long col = ccol0 + j * 16;
      float badd_c = (bias_mode == 1) ? bias[col] : 0.0f;
#pragma unroll
      for (int r = 0; r < 4; ++r) {
        const long row = crow0 + i * 16 + r;
        float v = acc[i][j][r] * alpha + badd_c;
        if (bias_mode == 2) v += bias[row];
        if (OUTF)
          ((float*)Cb)[row * ldc + col] = v;
        else
          ((unsigned short*)Cb)[row * ldc + col] = f2b(v);
      }
    }
  }
}

// ---------------------------------------------------------------------------
// In-place row softmax over bf16 rows of length 4096. One block (256thr)/row.
// ---------------------------------------------------------------------------
__global__ __launch_bounds__(256)
void softmax_rows(unsigned short* __restrict__ S) {
  const int t = threadIdx.x;
  unsigned short* row = S + (size_t)blockIdx.x * 4096;
  const bf16x8* p = (const bf16x8*)row;
  bf16x8 u0 = p[t * 2], u1 = p[t * 2 + 1];

  float v[16];
  float m = -1e30f;
#pragma unroll
  for (int j = 0; j < 8; j++) { v[j] = b2f((unsigned short)u0[j]); }
#pragma unroll
  for (int j = 0; j < 8; j++) { v[8 + j] = b2f((unsigned short)u1[j]); }
#pragma unroll
  for (int j = 0; j < 16; j++) m = fmaxf(m, v[j]);

#pragma unroll
  for (int off = 32; off > 0; off >>= 1) m = fmaxf(m, __shfl_xor(m, off));
  __shared__ float redm[4];
  if ((t & 63) == 0) redm[t >> 6] = m;
  __syncthreads();
  m = fmaxf(fmaxf(redm[0], redm[1]), fmaxf(redm[2], redm[3]));

  float s = 0.0f;
#pragma unroll
  for (int j = 0; j < 16; j++) { v[j] = __expf(v[j] - m); s += v[j]; }
#pragma unroll
  for (int off = 32; off > 0; off >>= 1) s += __shfl_xor(s, off);
  __shared__ float reds[4];
  if ((t & 63) == 0) reds[t >> 6] = s;
  __syncthreads();
  s = reds[0] + reds[1] + reds[2] + reds[3];
  const float inv = 1.0f / s;

  bf16x8 o0, o1;
#pragma unroll
  for (int j = 0; j < 8; j++) o0[j] = (short)f2b(v[j] * inv);
#pragma unroll
  for (int j = 0; j < 8; j++) o1[j] = (short)f2b(v[8 + j] * inv);
  bf16x8* q = (bf16x8*)row;
  q[t * 2] = o0;
  q[t * 2 + 1] = o1;
}

// ---------------------------------------------------------------------------
extern "C" void kernel_launch(void* const* d_in, const int* in_sizes, int n_in,
                              void* d_out, int out_size, void* d_ws,
                              size_t ws_size, hipStream_t stream) {
  const float* x  = (const float*)d_in[0];
  const float* Wq = (const float*)d_in[1];
  const float* bq = (const float*)d_in[2];
  const float* Wk = (const float*)d_in[3];
  const float* bk = (const float*)d_in[4];
  const float* Wv = (const float*)d_in[5];
  const float* bv = (const float*)d_in[6];
  float* out = (float*)d_out;

  const int Bb = 4, S = 4096, D = 1024;
  const long BS = (long)Bb * S;                 // 16384
  const size_t MiB = 1u << 20;

  char* base = (char*)d_ws;
  unsigned short* Wqt = (unsigned short*)(base);              // 2 MiB
  unsigned short* Wkt = (unsigned short*)(base + 2 * MiB);    // 2
  unsigned short* Wvt = (unsigned short*)(base + 4 * MiB);    // 2
  unsigned short* Qb  = (unsigned short*)(base + 6 * MiB);    // 32
  unsigned short* Kb  = (unsigned short*)(base + 38 * MiB);   // 32
  unsigned short* Vt  = (unsigned short*)(base + 70 * MiB);   // 32  [D][BS]
  unsigned short* xb  = (unsigned short*)(base + 102 * MiB);  // 32 (dies early)
  unsigned short* Sb  = xb;  // scores region overlaps dead xb
  const bool batched = ws_size >= (size_t)(102 + 128) * MiB;  // 4-batch scores

  // 1. x -> bf16
  const int n8 = (int)(BS * D / 8);
  convert_x<<<n8 / 256, 256, 0, stream>>>(x, xb, n8);

  // 2. W -> W^T bf16
  dim3 tb(32, 8), tg(32, 32);
  transpose_w<<<tg, tb, 0, stream>>>(Wq, Wqt);
  transpose_w<<<tg, tb, 0, stream>>>(Wk, Wkt);
  transpose_w<<<tg, tb, 0, stream>>>(Wv, Wvt);

  // 3. projections
  gemm256<0><<<dim3(D / 256, BS / 256, 1), 512, 0, stream>>>(
      xb, D, 0, Wqt, D, 0, Qb, D, 0, bq, 1, D, 1.0f);
  gemm256<0><<<dim3(D / 256, BS / 256, 1), 512, 0, stream>>>(
      xb, D, 0, Wkt, D, 0, Kb, D, 0, bk, 1, D, 1.0f);
  gemm256<0><<<dim3(BS / 256, D / 256, 1), 512, 0, stream>>>(
      Wvt, D, 0, xb, D, 0, Vt, BS, 0, bv, 2, D, 1.0f);

  // 4. attention
  const float scale = 0.03125f;  // 1/sqrt(1024)
  if (batched) {
    gemm256<0><<<dim3(S / 256, S / 256, Bb), 512, 0, stream>>>(
        Qb, D, (long)S * D, Kb, D, (long)S * D, Sb, S, (long)S * S,
        nullptr, 0, D, scale);
    softmax_rows<<<Bb * S, 256, 0, stream>>>(Sb);
    gemm256<1><<<dim3(D / 256, S / 256, Bb), 512, 0, stream>>>(
        Sb, S, (long)S * S, Vt, BS, (long)S, out, D, (long)S * D,
        nullptr, 0, S, 1.0f);
  } else {
    for (int b = 0; b < Bb; b++) {
      const unsigned short* Qp = Qb + (long)b * S * D;
      const unsigned short* Kp = Kb + (long)b * S * D;
      gemm256<0><<<dim3(S / 256, S / 256, 1), 512, 0, stream>>>(
          Qp, D, 0, Kp, D, 0, Sb, S, 0, nullptr, 0, D, scale);
      softmax_rows<<<S, 256, 0, stream>>>(Sb);
      gemm256<1><<<dim3(D / 256, S / 256, 1), 512, 0, stream>>>(
          Sb, S, 0, Vt + (long)b * S, BS, 0, out + (long)b * S * D, D, 0,
          nullptr, 0, S, 1.0f);
    }
  }
}

// Round 5
// 463.854 us; speedup vs baseline: 1.5667x; 1.0107x over previous
//
#include <hip/hip_runtime.h>
#include <hip/hip_bf16.h>
#include <stdint.h>

// ---------------------------------------------------------------------------
// Self-attention forward, B=4 S=4096 D=1024, fp32 in -> f32 out.
// GEMM: 256x256 tile, BK=64, 8 waves, dbuf LDS, ONE barrier + ONE vmcnt(0)
// per K-tile, A-frag reads software-pipelined under MFMA, LDS XOR swizzle,
// setprio, XCD-chunked block swizzle (T1).
// ---------------------------------------------------------------------------

typedef __attribute__((ext_vector_type(8))) short bf16x8;
typedef __attribute__((ext_vector_type(4))) float f32x4;

static __device__ __forceinline__ unsigned short f2b(float f) {
  union { float f; unsigned u; } x; x.f = f;
  unsigned u = x.u;
  u += 0x7fffu + ((u >> 16) & 1u);      // RNE
  return (unsigned short)(u >> 16);
}
static __device__ __forceinline__ float b2f(unsigned short s) {
  union { unsigned u; float f; } x; x.u = ((unsigned)s) << 16;
  return x.f;
}

// async global->LDS, 16B per lane. LDS dest: wave-uniform base + lane*16.
static __device__ __forceinline__ void gl_lds16(const void* g, void* l) {
  __builtin_amdgcn_global_load_lds(
      (const __attribute__((address_space(1))) void*)(uintptr_t)(g),
      (__attribute__((address_space(3))) void*)(uint32_t)(uintptr_t)(l),
      16, 0, 0);
}

// ---------------------------------------------------------------------------
__global__ void convert_x(const float* __restrict__ in,
                          unsigned short* __restrict__ out, int n8) {
  int i = blockIdx.x * blockDim.x + threadIdx.x;
  if (i >= n8) return;
  const float4* p = (const float4*)in + (size_t)i * 2;
  float4 a = p[0], b = p[1];
  bf16x8 o;
  o[0] = (short)f2b(a.x); o[1] = (short)f2b(a.y);
  o[2] = (short)f2b(a.z); o[3] = (short)f2b(a.w);
  o[4] = (short)f2b(b.x); o[5] = (short)f2b(b.y);
  o[6] = (short)f2b(b.z); o[7] = (short)f2b(b.w);
  ((bf16x8*)out)[i] = o;
}

__global__ void transpose_w(const float* __restrict__ in,
                            unsigned short* __restrict__ out) {
  __shared__ float tile[32][33];
  const int tx = threadIdx.x;
  const int x = blockIdx.x * 32 + tx;
  const int y0 = blockIdx.y * 32;
  for (int j = threadIdx.y; j < 32; j += 8)
    tile[j][tx] = in[(size_t)(y0 + j) * 1024 + x];
  __syncthreads();
  const int ox = blockIdx.y * 32 + tx;
  const int oy0 = blockIdx.x * 32;
  for (int j = threadIdx.y; j < 32; j += 8)
    out[(size_t)(oy0 + j) * 1024 + ox] = f2b(tile[tx][j]);
}

// ---------------------------------------------------------------------------
// 256x256 NT GEMM, BK=64, 512 threads (8 waves, 2x4), dbuf LDS.
// C[m][n] = alpha * sum_k A[m][k]*B[n][k] (+bias). z-batched via strides.
// Requires M%256==0, N%256==0, K%64==0.
// ---------------------------------------------------------------------------
template <int OUTF>
__global__ __launch_bounds__(512, 2)
void gemm256(const unsigned short* __restrict__ A, long lda, long sAz,
             const unsigned short* __restrict__ B, long ldb, long sBz,
             void* __restrict__ Cv, long ldc, long sCz,
             const float* __restrict__ bias, int bias_mode,
             int K, float alpha) {
  __shared__ __align__(16) unsigned short As[2][256 * 64];
  __shared__ __align__(16) unsigned short Bs[2][256 * 64];

  // XCD-chunked block swizzle (T1): HW places block n on XCD n%8; remap so
  // consecutive TILE ids (which share A-panels) colocate on one XCD's L2.
  const unsigned gx = gridDim.x, gy = gridDim.y;
  const unsigned nwg = gx * gy * gridDim.z;
  const unsigned hwid = (blockIdx.z * gy + blockIdx.y) * gx + blockIdx.x;
  unsigned tile = hwid;
  if ((nwg & 7u) == 0u) tile = (hwid & 7u) * (nwg >> 3) + (hwid >> 3);
  const unsigned bxi = tile % gx;
  const unsigned byi = (tile / gx) % gy;
  const unsigned bzi = tile / (gx * gy);

  const int t = threadIdx.x;
  const int wid = t >> 6, lane = t & 63;
  const int wm = wid >> 2, wn = wid & 3;      // 2x4 wave grid
  const int fr = lane & 15, fq = lane >> 4;
  const long bm = (long)byi * 256;
  const long bn = (long)bxi * 256;
  const unsigned short* Ab = A + (size_t)bzi * sAz;
  const unsigned short* Bb = B + (size_t)bzi * sBz;

  // staging: one gl_lds call = 512 lanes x 16B = 64 rows x 64 cols bf16.
  // pre-swizzled global source (rule #21): col granule ^= row&7.
  const int sr = t >> 3;                       // 0..63 row in chunk
  const int scol = 8 * ((t & 7) ^ (sr & 7));   // swizzled col (elements)
  const unsigned short* Ag = Ab + (bm + sr) * lda + scol;
  const unsigned short* Bg = Bb + (bn + sr) * ldb + scol;
  const int ldsw = wid * 512;                  // wave chunk base (shorts)

  const int NT = K >> 6;
  f32x4 acc[8][4] = {};

#define STAGE(XS, Xg, ld, kt, h, bidx)                                        \
  do {                                                                        \
    gl_lds16(Xg + (size_t)((h) * 128) * (ld) + (size_t)(kt) * 64,             \
             &XS[bidx][(h) * 128 * 64 + ldsw]);                               \
    gl_lds16(Xg + (size_t)((h) * 128 + 64) * (ld) + (size_t)(kt) * 64,        \
             &XS[bidx][((h) * 128 + 64) * 64 + ldsw]);                        \
  } while (0)

  // swizzled ds_read: row-major [256][64] bf16, byte ^= (row&7)<<4
  auto rdA = [&](int bidx, int i, int kh) {
    int row = wm * 128 + i * 16 + fr;
    int inb = (kh * 64 + fq * 16) ^ ((fr & 7) << 4);
    return *(const bf16x8*)((const char*)&As[bidx][0] + row * 128 + inb);
  };
  auto rdB = [&](int bidx, int j, int kh) {
    int row = wn * 64 + j * 16 + fr;
    int inb = (kh * 64 + fq * 16) ^ ((fr & 7) << 4);
    return *(const bf16x8*)((const char*)&Bs[bidx][0] + row * 128 + inb);
  };

  // prologue: stage tile 0, drain, sync.
  STAGE(As, Ag, lda, 0, 0, 0); STAGE(As, Ag, lda, 0, 1, 0);
  STAGE(Bs, Bg, ldb, 0, 0, 0); STAGE(Bs, Bg, ldb, 0, 1, 0);
  asm volatile("s_waitcnt vmcnt(0)" ::: "memory");
  asm volatile("s_barrier" ::: "memory");

  for (int tt = 0; tt < NT; ++tt) {
    const int bidx = tt & 1;
    const int nb = (tt + 1) & 1;
    bf16x8 bfr[4][2], ar[2][2], arn[2][2];

    // all 8 B-frags + first A-pair
#pragma unroll
    for (int j = 0; j < 4; ++j) {
      bfr[j][0] = rdB(bidx, j, 0);
      bfr[j][1] = rdB(bidx, j, 1);
    }
#pragma unroll
    for (int ii = 0; ii < 2; ++ii) {
      ar[ii][0] = rdA(bidx, ii, 0);
      ar[ii][1] = rdA(bidx, ii, 1);
    }

    // stage tile t+1 as early as possible (writes land in the other buffer;
    // safe: that buffer's readers all finished before the last barrier).
    if (tt + 1 < NT) {
      STAGE(As, Ag, lda, tt + 1, 0, nb); STAGE(As, Ag, lda, tt + 1, 1, nb);
      STAGE(Bs, Bg, ldb, tt + 1, 0, nb); STAGE(Bs, Bg, ldb, tt + 1, 1, nb);
    }

    __builtin_amdgcn_s_setprio(1);
#pragma unroll
    for (int p = 0; p < 4; ++p) {
      // prefetch next A-pair into regs so its latency hides under this MFMA
      if (p < 3) {
#pragma unroll
        for (int ii = 0; ii < 2; ++ii) {
          arn[ii][0] = rdA(bidx, (p + 1) * 2 + ii, 0);
          arn[ii][1] = rdA(bidx, (p + 1) * 2 + ii, 1);
        }
      }
#pragma unroll
      for (int ii = 0; ii < 2; ++ii)
#pragma unroll
        for (int j = 0; j < 4; ++j) {
          acc[p * 2 + ii][j] = __builtin_amdgcn_mfma_f32_16x16x32_bf16(
              ar[ii][0], bfr[j][0], acc[p * 2 + ii][j], 0, 0, 0);
          acc[p * 2 + ii][j] = __builtin_amdgcn_mfma_f32_16x16x32_bf16(
              ar[ii][1], bfr[j][1], acc[p * 2 + ii][j], 0, 0, 0);
        }
      if (p < 3) {
#pragma unroll
        for (int ii = 0; ii < 2; ++ii) {
          ar[ii][0] = arn[ii][0];
          ar[ii][1] = arn[ii][1];
        }
      }
    }
    __builtin_amdgcn_s_setprio(0);

    // single drain + single barrier per K-tile (buffer transition).
    asm volatile("s_waitcnt vmcnt(0)" ::: "memory");
    asm volatile("s_barrier" ::: "memory");
  }
#undef STAGE

  // epilogue: C/D layout col=lane&15, row=(lane>>4)*4+reg  [m89/m91]
  char* Cb = (char*)Cv + (size_t)bzi * sCz * (OUTF ? 4 : 2);
  const long crow0 = bm + wm * 128 + fq * 4;
  const long ccol0 = bn + wn * 64 + fr;
#pragma unroll
  for (int i = 0; i < 8; ++i) {
#pragma unroll
    for (int j = 0; j < 4; ++j) {
      const long col = ccol0 + j * 16;
      float badd_c = (bias_mode == 1) ? bias[col] : 0.0f;
#pragma unroll
      for (int r = 0; r < 4; ++r) {
        const long row = crow0 + i * 16 + r;
        float v = acc[i][j][r] * alpha + badd_c;
        if (bias_mode == 2) v += bias[row];
        if (OUTF)
          ((float*)Cb)[row * ldc + col] = v;
        else
          ((unsigned short*)Cb)[row * ldc + col] = f2b(v);
      }
    }
  }
}

// ---------------------------------------------------------------------------
// In-place row softmax over bf16 rows of length 4096. One block (256thr)/row.
// ---------------------------------------------------------------------------
__global__ __launch_bounds__(256)
void softmax_rows(unsigned short* __restrict__ S) {
  const int t = threadIdx.x;
  unsigned short* row = S + (size_t)blockIdx.x * 4096;
  const bf16x8* p = (const bf16x8*)row;
  bf16x8 u0 = p[t * 2], u1 = p[t * 2 + 1];

  float v[16];
  float m = -1e30f;
#pragma unroll
  for (int j = 0; j < 8; j++) { v[j] = b2f((unsigned short)u0[j]); }
#pragma unroll
  for (int j = 0; j < 8; j++) { v[8 + j] = b2f((unsigned short)u1[j]); }
#pragma unroll
  for (int j = 0; j < 16; j++) m = fmaxf(m, v[j]);

#pragma unroll
  for (int off = 32; off > 0; off >>= 1) m = fmaxf(m, __shfl_xor(m, off));
  __shared__ float redm[4];
  if ((t & 63) == 0) redm[t >> 6] = m;
  __syncthreads();
  m = fmaxf(fmaxf(redm[0], redm[1]), fmaxf(redm[2], redm[3]));

  float s = 0.0f;
#pragma unroll
  for (int j = 0; j < 16; j++) { v[j] = __expf(v[j] - m); s += v[j]; }
#pragma unroll
  for (int off = 32; off > 0; off >>= 1) s += __shfl_xor(s, off);
  __shared__ float reds[4];
  if ((t & 63) == 0) reds[t >> 6] = s;
  __syncthreads();
  s = reds[0] + reds[1] + reds[2] + reds[3];
  const float inv = 1.0f / s;

  bf16x8 o0, o1;
#pragma unroll
  for (int j = 0; j < 8; j++) o0[j] = (short)f2b(v[j] * inv);
#pragma unroll
  for (int j = 0; j < 8; j++) o1[j] = (short)f2b(v[8 + j] * inv);
  bf16x8* q = (bf16x8*)row;
  q[t * 2] = o0;
  q[t * 2 + 1] = o1;
}

// ---------------------------------------------------------------------------
extern "C" void kernel_launch(void* const* d_in, const int* in_sizes, int n_in,
                              void* d_out, int out_size, void* d_ws,
                              size_t ws_size, hipStream_t stream) {
  const float* x  = (const float*)d_in[0];
  const float* Wq = (const float*)d_in[1];
  const float* bq = (const float*)d_in[2];
  const float* Wk = (const float*)d_in[3];
  const float* bk = (const float*)d_in[4];
  const float* Wv = (const float*)d_in[5];
  const float* bv = (const float*)d_in[6];
  float* out = (float*)d_out;

  const int Bb = 4, S = 4096, D = 1024;
  const long BS = (long)Bb * S;                 // 16384
  const size_t MiB = 1u << 20;

  char* base = (char*)d_ws;
  unsigned short* Wqt = (unsigned short*)(base);              // 2 MiB
  unsigned short* Wkt = (unsigned short*)(base + 2 * MiB);    // 2
  unsigned short* Wvt = (unsigned short*)(base + 4 * MiB);    // 2
  unsigned short* Qb  = (unsigned short*)(base + 6 * MiB);    // 32
  unsigned short* Kb  = (unsigned short*)(base + 38 * MiB);   // 32
  unsigned short* Vt  = (unsigned short*)(base + 70 * MiB);   // 32  [D][BS]
  unsigned short* xb  = (unsigned short*)(base + 102 * MiB);  // 32 (dies early)
  unsigned short* Sb  = xb;  // scores region overlaps dead xb
  const bool batched = ws_size >= (size_t)(102 + 128) * MiB;  // 4-batch scores

  // 1. x -> bf16
  const int n8 = (int)(BS * D / 8);
  convert_x<<<n8 / 256, 256, 0, stream>>>(x, xb, n8);

  // 2. W -> W^T bf16
  dim3 tb(32, 8), tg(32, 32);
  transpose_w<<<tg, tb, 0, stream>>>(Wq, Wqt);
  transpose_w<<<tg, tb, 0, stream>>>(Wk, Wkt);
  transpose_w<<<tg, tb, 0, stream>>>(Wv, Wvt);

  // 3. projections
  gemm256<0><<<dim3(D / 256, BS / 256, 1), 512, 0, stream>>>(
      xb, D, 0, Wqt, D, 0, Qb, D, 0, bq, 1, D, 1.0f);
  gemm256<0><<<dim3(D / 256, BS / 256, 1), 512, 0, stream>>>(
      xb, D, 0, Wkt, D, 0, Kb, D, 0, bk, 1, D, 1.0f);
  gemm256<0><<<dim3(BS / 256, D / 256, 1), 512, 0, stream>>>(
      Wvt, D, 0, xb, D, 0, Vt, BS, 0, bv, 2, D, 1.0f);

  // 4. attention
  const float scale = 0.03125f;  // 1/sqrt(1024)
  if (batched) {
    gemm256<0><<<dim3(S / 256, S / 256, Bb), 512, 0, stream>>>(
        Qb, D, (long)S * D, Kb, D, (long)S * D, Sb, S, (long)S * S,
        nullptr, 0, D, scale);
    softmax_rows<<<Bb * S, 256, 0, stream>>>(Sb);
    gemm256<1><<<dim3(D / 256, S / 256, Bb), 512, 0, stream>>>(
        Sb, S, (long)S * S, Vt, BS, (long)S, out, D, (long)S * D,
        nullptr, 0, S, 1.0f);
  } else {
    for (int b = 0; b < Bb; b++) {
      const unsigned short* Qp = Qb + (long)b * S * D;
      const unsigned short* Kp = Kb + (long)b * S * D;
      gemm256<0><<<dim3(S / 256, S / 256, 1), 512, 0, stream>>>(
          Qp, D, 0, Kp, D, 0, Sb, S, 0, nullptr, 0, D, scale);
      softmax_rows<<<S, 256, 0, stream>>>(Sb);
      gemm256<1><<<dim3(D / 256, S / 256, 1), 512, 0, stream>>>(
          Sb, S, 0, Vt + (long)b * S, BS, 0, out + (long)b * S * D, D, 0,
          nullptr, 0, S, 1.0f);
    }
  }
}